// Round 12
// baseline (391.265 us; speedup 1.0000x reference)
//
#include <hip/hip_runtime.h>

#define NSLOT 256
#define GAP_THR 5.0e-5f
#define PP 8

typedef float f32x4 __attribute__((ext_vector_type(4)));

// prep: zero 16384 aux floats; wf[(d4*32+o)*4+k] = W[o][d4*4+k] (f32, chunk-transposed);
// wdf[o*128+k] = (double)W[o][k]
__global__ __launch_bounds__(256) void prep_kernel(const float* __restrict__ W,
                                                   float* __restrict__ wf,
                                                   double* __restrict__ wdf,
                                                   float* __restrict__ ws) {
  int i = blockIdx.x * 256 + threadIdx.x;   // grid 64 -> 16384
  ws[i] = 0.0f;
  if (i < 4096) {
    int d4 = i >> 7;
    int o  = (i >> 2) & 31;
    int k  = i & 3;
    wf[i]  = W[(o << 7) + (d4 << 2) + k];
    wdf[i] = (double)W[i];
  }
}

// ws layout: floats [0:16384) aux slots; byte 65536: wf f32 (16KB); byte 81920: wdf f64 (32KB)
__global__ __launch_bounds__(512, 4) void moe_router_kernel(
    const float* __restrict__ x, const float* __restrict__ wf,
    const double* __restrict__ wdf, float* __restrict__ y,
    float* __restrict__ ws) {
  // Xs: double-buffered; each buf = 64 rows x 32 chunks of 16B, chunk XOR-swizzled
  // (phys p holds logical d4 = p ^ (row&31))
  __shared__ float Xs[2 * 8192];           // 65536 B
  __shared__ float m1s[8][64];             // 2048
  __shared__ float m2s[8][64];             // 2048
  __shared__ float m3s[8][64];             // 2048  exact f32 third-place
  __shared__ float sumS[8][64];            // 2048
  __shared__ int   jps[8][64];             // 2048  -> total 75776 B -> 2 blocks/CU

  const int tid = threadIdx.x;
  const int l   = tid & 63;                                  // lane (= row in B/C)
  const int wu  = __builtin_amdgcn_readfirstlane(tid >> 6);  // wave 0..7 -> 4-o slice
  const int p0  = blockIdx.x * PP;                           // first token-pair

  const f32x4* __restrict__ wv = reinterpret_cast<const f32x4*>(wf);
  const int rsw  = l & 31;

  // ---- staging helper: pair pi -> Xs[buf] via global_load_lds (pre-swizzled src) ----
  auto stage = [&](int pi, int buf) {
    const float* xb = x + ((size_t)(pi >> 10) * 32 * 2048 + ((pi & 1023) << 1)) * 128;
    auto ldsX = (__attribute__((address_space(3))) char*)&Xs[buf << 13];
    #pragma unroll
    for (int rep = 0; rep < 4; ++rep) {
      int i   = (rep << 9) + tid;           // 0..2047 = linear 16B chunk index
      int row = i >> 5;                     // 0..63
      int p   = i & 31;                     // physical chunk
      int h   = row & 31, t = row >> 5;
      int d4  = p ^ (row & 31);             // logical chunk stored at p
      const float* src = xb + ((size_t)h * 2048 + t) * 128 + (d4 << 2);
      __builtin_amdgcn_global_load_lds(
          (const __attribute__((address_space(1))) void*)src,
          (__attribute__((address_space(3))) void*)(ldsX + (size_t)i * 16),
          16, 0, 0);
    }
  };

  stage(p0, 0);

  for (int it = 0; it < PP; ++it) {
    const int cur = it & 1;
    const int pc  = p0 + it;
    // issue next-pair staging BEFORE waiting (counted vmcnt keeps it in flight)
    if (it + 1 < PP) {
      stage(pc + 1, cur ^ 1);
      asm volatile("s_waitcnt vmcnt(4)" ::: "memory");   // current buf's 4 loads done
    } else {
      asm volatile("s_waitcnt vmcnt(0)" ::: "memory");
    }
    __builtin_amdgcn_s_barrier();

    const int xb0  = cur << 13;
    const int base = xb0 + (l << 7);

    // ---- phase B: 4 f32 dots per lane (row = l); W via wave-uniform scalar loads ----
    f32x4 A0 = {0,0,0,0}, A1 = {0,0,0,0}, A2 = {0,0,0,0}, A3 = {0,0,0,0};
    f32x4 xv = *reinterpret_cast<const f32x4*>(&Xs[base + (rsw << 2)]);
    #pragma unroll 4
    for (int d4 = 0; d4 < 32; ++d4) {
      f32x4 xn = *reinterpret_cast<const f32x4*>(
          &Xs[base + ((((d4 + 1) & 31) ^ rsw) << 2)]);
      const f32x4* wc = wv + (d4 << 5) + (wu << 2);   // 4 o-rows, wave-uniform
      f32x4 w0 = wc[0], w1 = wc[1], w2 = wc[2], w3 = wc[3];
      A0 += xv * w0;
      A1 += xv * w1;
      A2 += xv * w2;
      A3 += xv * w3;
      xv = xn;
    }
    float lv[4];
    lv[0] = (A0.x + A0.y) + (A0.z + A0.w);
    lv[1] = (A1.x + A1.y) + (A1.z + A1.w);
    lv[2] = (A2.x + A2.y) + (A2.z + A2.w);
    lv[3] = (A3.x + A3.y) + (A3.z + A3.w);

    // ---- local top-3 of this wave's 4 o's ----
    float m1 = lv[0], m2 = -3.0e38f, m3 = -3.0e38f;
    int   j1 = 0, j2 = 0;
    #pragma unroll
    for (int j = 1; j < 4; ++j) {
      float v = lv[j];
      if (v > m1)      { m3 = m2; m2 = m1; j2 = j1; m1 = v; j1 = j; }
      else if (v > m2) { m3 = m2; m2 = v; j2 = j; }
      else if (v > m3) { m3 = v; }
    }
    float e[4];
    float sloc = 0.0f;
    #pragma unroll
    for (int j = 0; j < 4; ++j) { e[j] = __expf(lv[j] - m1); sloc += e[j]; }

    m1s[wu][l]  = m1;
    m2s[wu][l]  = m2;
    m3s[wu][l]  = m3;
    sumS[wu][l] = sloc;
    jps[wu][l]  = (j1 + (wu << 2)) | ((j2 + (wu << 2)) << 8);
    asm volatile("s_waitcnt lgkmcnt(0)" ::: "memory");
    __builtin_amdgcn_s_barrier();

    // ---- merge 8 per-wave top-3 summaries (redundant per wave; lane = row) ----
    float M1 = -3.0e38f, M2 = -3.0e38f, M3 = -3.0e38f;
    int g1 = 0, g2 = 0;
    #pragma unroll
    for (int w = 0; w < 8; ++w) {
      float a  = m1s[w][l];
      float bb = m2s[w][l];
      float c3 = m3s[w][l];
      int   jp = jps[w][l];
      int ja = jp & 255, jb = (jp >> 8) & 255;
      if (a > M1)      { M3 = M2; M2 = M1; g2 = g1; M1 = a; g1 = ja; }
      else if (a > M2) { M3 = M2; M2 = a; g2 = ja; }
      else if (a > M3) { M3 = a; }
      if (bb > M2)     { M3 = M2; M2 = bb; g2 = jb; }
      else if (bb > M3){ M3 = bb; }
      if (c3 > M3)     { M3 = c3; }
    }
    float S = 0.0f;
    #pragma unroll
    for (int w = 0; w < 8; ++w)
      S += sumS[w][l] * __expf(m1s[w][l] - M1);
    const float invS = 1.0f / S;
    float p1 = invS;
    float p2 = __expf(M2 - M1) * invS;
    int   j1g = g1, j2g = g2;

    // ---- exact-f64 guard: only when rank-2|3 gap is inside the f32 error band ----
    if (M2 - M3 < GAP_THR) {
      double Md = -1.0e300, M2d = -1.0e300;
      int Aa = 0, Ab = 0;
      #pragma unroll 1
      for (int o = 0; o < 32; ++o) {
        const double* wrow = wdf + (o << 7);
        double s = 0.0;
        #pragma unroll 4
        for (int k4 = 0; k4 < 32; ++k4) {
          f32x4 xq = *reinterpret_cast<const f32x4*>(&Xs[base + ((k4 ^ rsw) << 2)]);
          const double* wk = wrow + (k4 << 2);
          s = fma((double)xq.x, wk[0], s);
          s = fma((double)xq.y, wk[1], s);
          s = fma((double)xq.z, wk[2], s);
          s = fma((double)xq.w, wk[3], s);
        }
        if (s > Md)       { M2d = Md; Ab = Aa; Md = s; Aa = o; }
        else if (s > M2d) { M2d = s; Ab = o; }
      }
      j1g = Aa; j2g = Ab;
      p1 = __expf((float)(Md  - (double)M1)) * invS;
      p2 = __expf((float)(M2d - (double)M1)) * invS;
    }
    const int jpack = j1g | (j2g << 8);

    // ---- aux: this wave's 4-o slice of probs, shuffle-tree over 64 rows ----
    {
      const float fsc = __expf(m1 - M1) * invS;
      float ps[4];
      #pragma unroll
      for (int j = 0; j < 4; ++j) ps[j] = e[j] * fsc;
      #pragma unroll
      for (int m = 1; m < 64; m <<= 1) {
        #pragma unroll
        for (int j = 0; j < 4; ++j) ps[j] += __shfl_xor(ps[j], m, 64);
      }
      const int slot = (pc & (NSLOT - 1)) << 5;
      if (l == 0) {
        #pragma unroll
        for (int j = 0; j < 4; ++j) atomicAdd(&ws[slot + (wu << 2) + j], ps[j]);
      }
      if (wu == 0) {
        float cnt = 0.0f;
        #pragma unroll
        for (int o = 0; o < 32; ++o) {
          float cc = (float)(__popcll(__ballot(j1g == o)) + __popcll(__ballot(j2g == o)));
          if (l == o) cnt = cc;
        }
        if (l < 32) atomicAdd(&ws[8192 + slot + l], cnt);
      }
    }

    // ---- epilogue: coalesced y writes; p/j broadcast via shuffle ----
    float* yb = y + ((size_t)(pc >> 10) * 32 * 2048 + ((pc & 1023) << 1)) * 128;
    #pragma unroll
    for (int rep = 0; rep < 4; ++rep) {
      int i   = (rep << 9) + tid;
      int row = i >> 5;
      int d4  = i & 31;
      float q1 = __shfl(p1, row, 64);
      float q2 = __shfl(p2, row, 64);
      int   jp = __shfl(jpack, row, 64);
      int i1 = jp & 255, i2 = (jp >> 8) & 255;
      int t = row >> 5, h = row & 31;
      const f32x4 A  = *reinterpret_cast<const f32x4*>(
          &Xs[xb0 + ((((t << 5) + i1) << 7)) + ((d4 ^ i1) << 2)]);
      const f32x4 Bv = *reinterpret_cast<const f32x4*>(
          &Xs[xb0 + ((((t << 5) + i2) << 7)) + ((d4 ^ i2) << 2)]);
      f32x4 o4 = q1 * A + q2 * Bv;
      __builtin_nontemporal_store(o4,
          reinterpret_cast<f32x4*>(yb + ((size_t)h * 2048 + t) * 128 + (d4 << 2)));
    }

    // protect buf(cur) from being re-staged until all waves finished reading it
    __builtin_amdgcn_s_barrier();
  }
}

__global__ __launch_bounds__(256) void finalize_kernel(const float* __restrict__ ws,
                                                       float* __restrict__ out_aux) {
  __shared__ double redP[8][32];
  __shared__ double redC[8][32];
  const int o = threadIdx.x & 31;
  const int g = threadIdx.x >> 5;
  double sp = 0.0, sc = 0.0;
  for (int s = g; s < NSLOT; s += 8) {
    sp += (double)ws[s * 32 + o];
    sc += (double)ws[8192 + s * 32 + o];
  }
  redP[g][o] = sp;
  redC[g][o] = sc;
  __syncthreads();
  if (threadIdx.x == 0) {
    double aux = 0.0;
    const double nrows  = 524288.0;          // B*H*C
    const double ntotal = 1048576.0;         // nrows * K
    for (int oo = 0; oo < 32; ++oo) {
      double tp = 0.0, tc = 0.0;
      for (int gg = 0; gg < 8; ++gg) { tp += redP[gg][oo]; tc += redC[gg][oo]; }
      aux += (tp / nrows) * (tc / ntotal);
    }
    out_aux[0] = (float)(0.01 * 32.0 * aux);
  }
}

extern "C" void kernel_launch(void* const* d_in, const int* in_sizes, int n_in,
                              void* d_out, int out_size, void* d_ws, size_t ws_size,
                              hipStream_t stream) {
  const float* x = (const float*)d_in[0];
  const float* W = (const float*)d_in[1];
  float*  y   = (float*)d_out;
  float*  ws  = (float*)d_ws;
  float*  wf  = (float*)((char*)d_ws + 65536);
  double* wdf = (double*)((char*)d_ws + 81920);

  prep_kernel<<<64, 256, 0, stream>>>(W, wf, wdf, ws);
  moe_router_kernel<<<8192 / PP, 512, 0, stream>>>(x, wf, wdf, y, ws);
  finalize_kernel<<<1, 256, 0, stream>>>(ws, y + (size_t)8 * 32 * 2048 * 128);
}

// Round 13
// 176.587 us; speedup vs baseline: 2.2157x; 2.2157x over previous
//
#include <hip/hip_runtime.h>

#define NSLOT 256

typedef double dbl4 __attribute__((ext_vector_type(4)));
typedef float  f32x4 __attribute__((ext_vector_type(4)));

// prep: zero the 16384 aux accumulation floats; convert W to f64 chunk-transposed:
// wd[(d4*32 + o)*4 + k] = W[o][d4*4 + k]
__global__ __launch_bounds__(256) void prep_kernel(const float* __restrict__ W,
                                                   double* __restrict__ wd,
                                                   float* __restrict__ ws) {
  int i = blockIdx.x * 256 + threadIdx.x;   // grid 64 -> 16384 threads
  ws[i] = 0.0f;
  if (i < 4096) {
    int d4 = i >> 7;
    int o  = (i >> 2) & 31;
    int k  = i & 3;
    wd[i] = (double)W[(o << 7) + (d4 << 2) + k];
  }
}

// ws layout: floats [0:8192) prob psum slots, [8192:16384) count slots; byte 65536+: W-f64 (32KB)
__global__ __launch_bounds__(512, 8) void moe_router_kernel(
    const float* __restrict__ x, const double* __restrict__ wd,
    float* __restrict__ y, float* __restrict__ ws) {
  // Xs: 64 rows x 32 chunks of 16B, chunk XOR-swizzled: phys p holds logical d4 = p ^ (row&31)
  __shared__ float  Xs[64 * 128];          // 32768 B
  __shared__ double m1s[8][64];            // 4096
  __shared__ float  sumS[8][64];           // 2048
  __shared__ unsigned short j1s[8][64];    // 1024
  __shared__ double m2x[64];               // 512
  __shared__ unsigned short j2x[64];       // 128   -> total 40576 B -> 4 blocks/CU

  const int tid = threadIdx.x;
  const int l   = tid & 63;                                  // lane (= row in B/C)
  const int wu  = __builtin_amdgcn_readfirstlane(tid >> 6);  // wave id 0..7 -> o-quad
  const int bc  = blockIdx.x;                                // 0..8191
  const int b   = bc >> 10;
  const int c0  = (bc & 1023) << 1;                          // 2 tokens per block

  const float* xb = x + ((size_t)b * 32 * 2048 + c0) * 128;

  // ---- stage X via global_load_lds (linear LDS dest, pre-swizzled global src) ----
  {
    auto ldsX = (__attribute__((address_space(3))) char*)Xs;
    #pragma unroll
    for (int rep = 0; rep < 4; ++rep) {
      int i   = (rep << 9) + tid;           // 0..2047 = linear 16B chunk index
      int row = i >> 5;                     // 0..63
      int p   = i & 31;                     // physical chunk
      int h   = row & 31, t = row >> 5;
      int d4  = p ^ (row & 31);             // logical chunk stored at p
      const float* src = xb + ((size_t)h * 2048 + t) * 128 + (d4 << 2);
      __builtin_amdgcn_global_load_lds(
          (const __attribute__((address_space(1))) void*)src,
          (__attribute__((address_space(3))) void*)(ldsX + (size_t)i * 16),
          16, 0, 0);
    }
  }
  __syncthreads();

  // ---- phase B: 4 f64 dots per lane (row = l); W via wave-uniform scalar loads ----
  double a0 = 0.0, a1 = 0.0, a2 = 0.0, a3 = 0.0;
  const dbl4* __restrict__ wv4 = reinterpret_cast<const dbl4*>(wd);
  const int rsw  = l & 31;
  const int base = l << 7;
  float4 xv = *reinterpret_cast<const float4*>(&Xs[base + (rsw << 2)]);  // chunk 0^rsw
  #pragma unroll 4
  for (int d4 = 0; d4 < 32; ++d4) {
    // branch-free prefetch of next chunk (wraps to 0 at the end, harmless)
    float4 xn = *reinterpret_cast<const float4*>(
        &Xs[base + ((((d4 + 1) & 31) ^ rsw) << 2)]);
    const dbl4* wc = wv4 + (d4 << 5) + (wu << 2);
    dbl4 w0 = wc[0], w1 = wc[1], w2 = wc[2], w3 = wc[3];
    double x0 = (double)xv.x, x1 = (double)xv.y, x2 = (double)xv.z, x3 = (double)xv.w;
    a0 = fma(x0, w0[0], a0); a0 = fma(x1, w0[1], a0);
    a0 = fma(x2, w0[2], a0); a0 = fma(x3, w0[3], a0);
    a1 = fma(x0, w1[0], a1); a1 = fma(x1, w1[1], a1);
    a1 = fma(x2, w1[2], a1); a1 = fma(x3, w1[3], a1);
    a2 = fma(x0, w2[0], a2); a2 = fma(x1, w2[1], a2);
    a2 = fma(x2, w2[2], a2); a2 = fma(x3, w2[3], a2);
    a3 = fma(x0, w3[0], a3); a3 = fma(x1, w3[1], a3);
    a3 = fma(x2, w3[2], a3); a3 = fma(x3, w3[3], a3);
    xv = xn;
  }

  // ---- local top-2 + exp-sum over this wave's 4 o's (in registers) ----
  double acc[4] = {a0, a1, a2, a3};
  double m1 = acc[0], m2 = -1.0e300;
  int    j1 = 0, j2 = 0;
  #pragma unroll
  for (int j = 1; j < 4; ++j) {
    double v = acc[j];
    if (v > m1)      { m2 = m1; j2 = j1; m1 = v; j1 = j; }
    else if (v > m2) { m2 = v; j2 = j; }
  }
  float e[4];
  float sloc = 0.0f;
  #pragma unroll
  for (int j = 0; j < 4; ++j) { e[j] = __expf((float)(acc[j] - m1)); sloc += e[j]; }

  m1s[wu][l]  = m1;
  sumS[wu][l] = sloc;
  j1s[wu][l]  = (unsigned short)(j1 + (wu << 2));
  __syncthreads();

  // ---- pass 1: global max + second-max-of-maxima + argmax wave (per row = lane) ----
  double M1 = -1.0e300, Ms = -1.0e300;
  int g1 = 0, gs = 0, wstar = 0;
  #pragma unroll
  for (int w = 0; w < 8; ++w) {
    double a = m1s[w][l];
    int   ja = j1s[w][l];
    if (a > M1)      { Ms = M1; gs = g1; M1 = a; g1 = ja; wstar = w; }
    else if (a > Ms) { Ms = a; gs = ja; }
  }
  // only the argmax wave contributes its in-register local m2/j2 for rows it owns
  if (wu == wstar) {
    m2x[l] = m2;
    j2x[l] = (unsigned short)(j2 + (wu << 2));
  }
  __syncthreads();

  double M2; int g2;
  {
    double mw = m2x[l];
    int    jw = j2x[l];
    if (mw > Ms) { M2 = mw; g2 = jw; }
    else         { M2 = Ms; g2 = gs; }
  }
  float S = 0.0f;
  #pragma unroll
  for (int w = 0; w < 8; ++w)
    S += sumS[w][l] * __expf((float)(m1s[w][l] - M1));
  const float invS = 1.0f / S;
  const float p1 = invS;                              // exp(M1-M1)/S
  const float p2 = __expf((float)(M2 - M1)) * invS;
  const int   jpack = g1 | (g2 << 8);

  // ---- aux prob column-sums: rescale own-wave exps, shuffle-tree over 64 rows ----
  {
    const float f = __expf((float)(m1 - M1)) * invS;
    float ps[4];
    #pragma unroll
    for (int j = 0; j < 4; ++j) ps[j] = e[j] * f;
    #pragma unroll
    for (int m = 1; m < 64; m <<= 1) {
      #pragma unroll
      for (int j = 0; j < 4; ++j) ps[j] += __shfl_xor(ps[j], m, 64);
    }
    const int slot = (bc & (NSLOT - 1)) << 5;
    if (l == 0) {
      #pragma unroll
      for (int j = 0; j < 4; ++j) atomicAdd(&ws[slot + (wu << 2) + j], ps[j]);
    }
    // counts via ballot (wave 0 only)
    if (wu == 0) {
      float cnt = 0.0f;
      #pragma unroll
      for (int o = 0; o < 32; ++o) {
        float c = (float)(__popcll(__ballot(g1 == o)) + __popcll(__ballot(g2 == o)));
        if (l == o) cnt = c;
      }
      if (l < 32) atomicAdd(&ws[8192 + slot + l], cnt);
    }
  }

  // ---- epilogue: coalesced y writes; p/j broadcast via shuffle ----
  float* yb = y + ((size_t)b * 32 * 2048 + c0) * 128;
  #pragma unroll
  for (int rep = 0; rep < 4; ++rep) {
    int i   = (rep << 9) + tid;
    int row = i >> 5;                    // row whose chunk this thread writes
    int d4  = i & 31;                    // logical chunk
    float q1 = __shfl(p1, row, 64);
    float q2 = __shfl(p2, row, 64);
    int   jp = __shfl(jpack, row, 64);
    int i1 = jp & 255, i2 = (jp >> 8) & 255;
    int t = row >> 5, h = row & 31;
    const float4 A  = *reinterpret_cast<const float4*>(
        &Xs[(((t << 5) + i1) << 7) + ((d4 ^ i1) << 2)]);
    const float4 Bv = *reinterpret_cast<const float4*>(
        &Xs[(((t << 5) + i2) << 7) + ((d4 ^ i2) << 2)]);
    f32x4 o4;
    o4.x = q1 * A.x + q2 * Bv.x;
    o4.y = q1 * A.y + q2 * Bv.y;
    o4.z = q1 * A.z + q2 * Bv.z;
    o4.w = q1 * A.w + q2 * Bv.w;
    __builtin_nontemporal_store(o4,
        reinterpret_cast<f32x4*>(yb + ((size_t)h * 2048 + t) * 128 + (d4 << 2)));
  }
}

__global__ __launch_bounds__(256) void finalize_kernel(const float* __restrict__ ws,
                                                       float* __restrict__ out_aux) {
  __shared__ double redP[8][32];
  __shared__ double redC[8][32];
  const int o = threadIdx.x & 31;
  const int g = threadIdx.x >> 5;
  double sp = 0.0, sc = 0.0;
  for (int s = g; s < NSLOT; s += 8) {
    sp += (double)ws[s * 32 + o];
    sc += (double)ws[8192 + s * 32 + o];
  }
  redP[g][o] = sp;
  redC[g][o] = sc;
  __syncthreads();
  if (threadIdx.x == 0) {
    double aux = 0.0;
    const double nrows  = 524288.0;          // B*H*C
    const double ntotal = 1048576.0;         // nrows * K
    for (int oo = 0; oo < 32; ++oo) {
      double tp = 0.0, tc = 0.0;
      for (int gg = 0; gg < 8; ++gg) { tp += redP[gg][oo]; tc += redC[gg][oo]; }
      aux += (tp / nrows) * (tc / ntotal);
    }
    out_aux[0] = (float)(0.01 * 32.0 * aux);
  }
}

extern "C" void kernel_launch(void* const* d_in, const int* in_sizes, int n_in,
                              void* d_out, int out_size, void* d_ws, size_t ws_size,
                              hipStream_t stream) {
  const float* x = (const float*)d_in[0];
  const float* W = (const float*)d_in[1];
  float*  y  = (float*)d_out;
  float*  ws = (float*)d_ws;
  double* wd = (double*)((char*)d_ws + 65536);

  prep_kernel<<<64, 256, 0, stream>>>(W, wd, ws);
  moe_router_kernel<<<8192, 512, 0, stream>>>(x, wd, y, ws);
  finalize_kernel<<<1, 256, 0, stream>>>(ws, y + (size_t)8 * 32 * 2048 * 128);
}